// Round 1
// 2639.188 us; speedup vs baseline: 1.1504x; 1.1504x over previous
//
#include <hip/hip_runtime.h>
#include <math.h>

#define BB 4
#define TT 10
#define HH 96
#define WW 96
#define HWSZ 9216
#define LL 5

typedef _Float16 half8 __attribute__((ext_vector_type(8)));
typedef _Float16 half4 __attribute__((ext_vector_type(4)));
typedef float floatx4 __attribute__((ext_vector_type(4)));

// ---------------- prep: weights -> f16, MFMA-friendly [co][k] layouts ----------------
// wi16/wh16: [co=32][k=1600], k = tap*64 + ci   (tap = ky*5+kx)
// wA16:      [co=192][k=576], k = tap*64 + ci   (tap = ky*3+kx)
// rw16:      [co=192][k=320], k = l*64 + c
// fw16:      [co=16(10 live)][k=800], k = tap*32 + ci
__global__ __launch_bounds__(256) void prep_weights(const float* __restrict__ i2f_w,
                                                    const float* __restrict__ h2f_w,
                                                    const float* __restrict__ i2h_w,
                                                    const float* __restrict__ ret_w,
                                                    const float* __restrict__ flows_w,
                                                    _Float16* __restrict__ wi16,
                                                    _Float16* __restrict__ wh16,
                                                    _Float16* __restrict__ wA16,
                                                    _Float16* __restrict__ rw16,
                                                    _Float16* __restrict__ fw16) {
    const int id = blockIdx.x * 256 + threadIdx.x;   // 0..287231
    if (id < 51200) {
        const int co = id / 1600, k = id % 1600, tap = k >> 6, ci = k & 63;
        wi16[id] = (_Float16)i2f_w[(co * 64 + ci) * 25 + tap];
    } else if (id < 102400) {
        const int r = id - 51200;
        const int co = r / 1600, k = r % 1600, tap = k >> 6, ci = k & 63;
        wh16[r] = (_Float16)h2f_w[(co * 64 + ci) * 25 + tap];
    } else if (id < 212992) {
        const int r = id - 102400;
        const int co = r / 576, k = r % 576, tap = k >> 6, ci = k & 63;
        wA16[r] = (_Float16)i2h_w[(co * 64 + ci) * 9 + tap];
    } else if (id < 274432) {
        const int r = id - 212992;
        rw16[r] = (_Float16)ret_w[r];   // already [co][320] with k = l*64+c
    } else {
        const int r = id - 274432;      // 0..12799
        const int co = r / 800, k = r % 800, tap = k >> 5, ci = k & 31;
        fw16[r] = (co < 10) ? (_Float16)flows_w[(co * 32 + ci) * 25 + tap] : (_Float16)0.0f;
    }
}

// ---------------- prep: x -> f16 channel-last x16[img][pos][ci], img flat ----
__global__ __launch_bounds__(256) void prep_x16(const float* __restrict__ x,
                                                _Float16* __restrict__ x16) {
    const int id = blockIdx.x * 256 + threadIdx.x;   // 0..368639
    const int img = id / HWSZ, pos = id % HWSZ;
    const float* src = x + (size_t)img * 64 * HWSZ + pos;
    _Float16* dst = x16 + ((size_t)img * HWSZ + pos) * 64;
    #pragma unroll
    for (int i = 0; i < 8; i++) {
        half8 v;
        #pragma unroll
        for (int j = 0; j < 8; j++)
            v[j] = (_Float16)src[(size_t)(i * 8 + j) * HWSZ];
        *(half8*)(dst + i * 8) = v;
    }
}

// ---------------- i2h: 3x3 conv as MFMA implicit GEMM, output f16 channel-last -------
// One BLOCK per n-tile (grid 2304); each wave owns 3 of the 12 m-tiles.
// image remap: step t, batch b reads flat image q = t*4 + b
__global__ __launch_bounds__(256) void i2h_mfma(const _Float16* __restrict__ x16,
                                                const _Float16* __restrict__ wA16,
                                                const float* __restrict__ bias,
                                                _Float16* __restrict__ i2h16, int t) {
    const int wv = threadIdx.x >> 6;
    const int ln = threadIdx.x & 63;
    const int lm = ln & 15, q = ln >> 4;
    const int nt = blockIdx.x;                   // 0..2303
    const int b  = nt / 576;
    const int ti = nt % 576;
    const int y  = ti / 6;
    const int x0 = (ti % 6) * 16;
    const _Float16* xb = x16 + (size_t)(t * BB + b) * HWSZ * 64;
    const int m0 = wv * 3;                       // this wave's m-tiles: m0..m0+2

    floatx4 acc[3];
    #pragma unroll
    for (int j = 0; j < 3; j++)
        #pragma unroll
        for (int r = 0; r < 4; r++)
            acc[j][r] = bias[(m0 + j) * 16 + q * 4 + r];

    for (int s = 0; s < 18; s++) {
        const int tap = s >> 1;
        const int ky = tap / 3 - 1, kx = tap % 3 - 1;
        const int ci0 = (s & 1) * 32;
        const int k0 = tap * 64 + ci0;
        const int gy = y + ky, gx = x0 + lm + kx;
        half8 bf = {};
        if (gy >= 0 && gy < HH && gx >= 0 && gx < WW)
            bf = *(const half8*)(xb + (size_t)(gy * WW + gx) * 64 + ci0 + q * 8);
        #pragma unroll
        for (int j = 0; j < 3; j++) {
            const half8 af = *(const half8*)(wA16 + (size_t)((m0 + j) * 16 + lm) * 576 + k0 + q * 8);
            acc[j] = __builtin_amdgcn_mfma_f32_16x16x32_f16(af, bf, acc[j], 0, 0, 0);
        }
    }
    const int pos = y * WW + x0 + lm;
    _Float16* op = i2h16 + ((size_t)b * HWSZ + pos) * 192;
    #pragma unroll
    for (int j = 0; j < 3; j++) {
        half4 pk;
        #pragma unroll
        for (int r = 0; r < 4; r++) pk[r] = (_Float16)acc[j][r];
        *(half4*)(op + (m0 + j) * 16 + q * 4) = pk;
    }
}

// ---------------- f1: tanh(conv5x5(x_t)+conv5x5(h)), one BLOCK per n-tile -------------
// 4-way K-split: wave = (phase, K-half), 25 s-iters each; LDS reduce; wave 0 epilogue.
__global__ __launch_bounds__(256) void f1_mfma(const _Float16* __restrict__ x16,
                                               const _Float16* __restrict__ h16,
                                               const _Float16* __restrict__ wi16,
                                               const _Float16* __restrict__ wh16,
                                               const float* __restrict__ bi,
                                               const float* __restrict__ bh,
                                               _Float16* __restrict__ f116, int t) {
    __shared__ float red[3][64][8];
    const int wv = threadIdx.x >> 6;
    const int ln = threadIdx.x & 63;
    const int lm = ln & 15, q = ln >> 4;
    const int nt = blockIdx.x;                   // 0..2303
    const int b  = nt / 576;
    const int ti = nt % 576;
    const int y  = ti / 6, xx = (ti % 6) * 16;

    floatx4 acc[2] = {};

    const _Float16* src = (wv & 2) ? (h16 + (size_t)b * HWSZ * 64)
                                   : (x16 + (size_t)(b * TT + t) * HWSZ * 64);
    const _Float16* wt  = (wv & 2) ? wh16 : wi16;
    const int s0 = (wv & 1) * 25;
    for (int s = s0; s < s0 + 25; s++) {
        const int tap = s >> 1;
        const int ky = tap / 5 - 2, kx = tap % 5 - 2;
        const int ci0 = (s & 1) * 32;
        const int k0 = tap * 64 + ci0;
        const int gy = y + ky, gx = xx + lm + kx;
        half8 bf = {};
        if (gy >= 0 && gy < HH && gx >= 0 && gx < WW)
            bf = *(const half8*)(src + (size_t)(gy * WW + gx) * 64 + ci0 + q * 8);
        const half8 a0 = *(const half8*)(wt + (size_t)(0 * 16 + lm) * 1600 + k0 + q * 8);
        const half8 a1 = *(const half8*)(wt + (size_t)(1 * 16 + lm) * 1600 + k0 + q * 8);
        acc[0] = __builtin_amdgcn_mfma_f32_16x16x32_f16(a0, bf, acc[0], 0, 0, 0);
        acc[1] = __builtin_amdgcn_mfma_f32_16x16x32_f16(a1, bf, acc[1], 0, 0, 0);
    }
    if (wv) {
        #pragma unroll
        for (int mt = 0; mt < 2; mt++)
            #pragma unroll
            for (int r = 0; r < 4; r++)
                red[wv - 1][ln][mt * 4 + r] = acc[mt][r];
    }
    __syncthreads();
    if (wv == 0) {
        #pragma unroll
        for (int w = 0; w < 3; w++)
            #pragma unroll
            for (int mt = 0; mt < 2; mt++)
                #pragma unroll
                for (int r = 0; r < 4; r++)
                    acc[mt][r] += red[w][ln][mt * 4 + r];
        const int pos = y * WW + xx + lm;
        _Float16* op = f116 + ((size_t)b * HWSZ + pos) * 32;
        #pragma unroll
        for (int mt = 0; mt < 2; mt++) {
            half4 pk;
            #pragma unroll
            for (int r = 0; r < 4; r++)
                pk[r] = (_Float16)tanhf(acc[mt][r] + bi[mt * 16 + q * 4 + r]
                                                   + bh[mt * 16 + q * 4 + r]);
            *(half4*)(op + mt * 16 + q * 4) = pk;
        }
    }
}

// ---------------- flows: conv5x5(f1,32->10), one BLOCK per n-tile, 4-way tap-split ----
__global__ __launch_bounds__(256) void flows_mfma(const _Float16* __restrict__ f116,
                                                  const _Float16* __restrict__ fw16,
                                                  const float* __restrict__ bias,
                                                  float* __restrict__ out) {
    __shared__ float red[3][64][4];
    const int wv = threadIdx.x >> 6;
    const int ln = threadIdx.x & 63;
    const int lm = ln & 15, q = ln >> 4;
    const int nt = blockIdx.x;                   // 0..2303
    const int b  = nt / 576;
    const int ti = nt % 576;
    const int y  = ti / 6, xx = (ti % 6) * 16;

    floatx4 acc = {};
    const _Float16* fb = f116 + (size_t)b * HWSZ * 32;
    const int t0 = (25 * wv) / 4, t1 = (25 * (wv + 1)) / 4;   // 6/6/6/7 taps
    for (int tap = t0; tap < t1; tap++) {
        const int ky = tap / 5 - 2, kx = tap % 5 - 2;
        const int gy = y + ky, gx = xx + lm + kx;
        half8 bf = {};
        if (gy >= 0 && gy < HH && gx >= 0 && gx < WW)
            bf = *(const half8*)(fb + (size_t)(gy * WW + gx) * 32 + q * 8);
        const half8 af = *(const half8*)(fw16 + (size_t)lm * 800 + tap * 32 + q * 8);
        acc = __builtin_amdgcn_mfma_f32_16x16x32_f16(af, bf, acc, 0, 0, 0);
    }
    if (wv) {
        #pragma unroll
        for (int r = 0; r < 4; r++) red[wv - 1][ln][r] = acc[r];
    }
    __syncthreads();
    if (wv == 0) {
        #pragma unroll
        for (int w = 0; w < 3; w++)
            #pragma unroll
            for (int r = 0; r < 4; r++) acc[r] += red[w][ln][r];
        const int pos = y * WW + xx + lm;
        #pragma unroll
        for (int r = 0; r < 4; r++) {
            const int c = q * 4 + r;
            if (c < 10)
                out[((size_t)b * 10 + c) * HWSZ + pos] = acc[r] + bias[c];
        }
    }
}

// ---------------- warp: bilinear warp of h16 by -flow, 2 threads per (b,l,pos) --------
__global__ __launch_bounds__(256) void warp_kernel(const _Float16* __restrict__ h16,
                                                   const float* __restrict__ flows,
                                                   _Float16* __restrict__ w16) {
    const int id = blockIdx.x * 256 + threadIdx.x;   // 0..18431
    const int p  = id >> 1;
    const int hf = (id & 1) * 32;                    // channel half: 0 or 32
    const int l = blockIdx.y;
    const int b = blockIdx.z;
    const int y = p / WW, xx = p % WW;
    const float f0  = -flows[((size_t)b * 10 + l * 2 + 0) * HWSZ + p];
    const float f1v = -flows[((size_t)b * 10 + l * 2 + 1) * HWSZ + p];
    const float nx = 2.0f * ((float)xx + f0)  / (float)(WW - 1) - 1.0f;
    const float ny = 2.0f * ((float)y  + f1v) / (float)(HH - 1) - 1.0f;
    const float fx = (nx + 1.0f) * (WW * 0.5f) - 0.5f;
    const float fy = (ny + 1.0f) * (HH * 0.5f) - 0.5f;
    const float x0f = floorf(fx), y0f = floorf(fy);
    const float wx = fx - x0f, wy = fy - y0f;
    const int x0 = (int)x0f, y0 = (int)y0f;

    int   off[4];
    float wgt[4];
    #pragma unroll
    for (int k = 0; k < 4; k++) {
        const int yi = y0 + (k >> 1);
        const int xi = x0 + (k & 1);
        const bool ok = (xi >= 0 && xi < WW && yi >= 0 && yi < HH);
        const int yc = min(max(yi, 0), HH - 1);
        const int xc = min(max(xi, 0), WW - 1);
        off[k] = yc * WW + xc;
        const float wk = ((k & 1) ? wx : 1.0f - wx) * ((k >> 1) ? wy : 1.0f - wy);
        wgt[k] = ok ? wk : 0.0f;
    }
    const _Float16* hb = h16 + (size_t)b * HWSZ * 64 + hf;
    _Float16* dst = w16 + ((size_t)b * HWSZ + p) * 320 + l * 64 + hf;
    #pragma unroll
    for (int i = 0; i < 4; i++) {
        const half8 v0 = *(const half8*)(hb + (size_t)off[0] * 64 + i * 8);
        const half8 v1 = *(const half8*)(hb + (size_t)off[1] * 64 + i * 8);
        const half8 v2 = *(const half8*)(hb + (size_t)off[2] * 64 + i * 8);
        const half8 v3 = *(const half8*)(hb + (size_t)off[3] * 64 + i * 8);
        half8 o;
        #pragma unroll
        for (int j = 0; j < 8; j++)
            o[j] = (_Float16)((float)v0[j] * wgt[0] + (float)v1[j] * wgt[1]
                            + (float)v2[j] * wgt[2] + (float)v3[j] * wgt[3]);
        *(half8*)(dst + i * 8) = o;
    }
}

// ---------------- h2h (1x1, 320->192) as MFMA + fused GRU gates -----------------------
// One BLOCK per n-tile; wave w owns m-tiles {w, w+4, w+8} = (r,u,m) for channels 16w..
__global__ __launch_bounds__(256) void gate_mfma(const _Float16* __restrict__ w16,
                                                 const _Float16* __restrict__ rw16,
                                                 const float* __restrict__ ret_b,
                                                 const _Float16* __restrict__ i2h16,
                                                 float* __restrict__ h,
                                                 _Float16* __restrict__ h16,
                                                 float* __restrict__ outs,
                                                 float* __restrict__ last_h, int t) {
    const int wv = threadIdx.x >> 6;
    const int ln = threadIdx.x & 63;
    const int lm = ln & 15, q = ln >> 4;
    const int nt = blockIdx.x;                   // 0..2303
    const int b  = nt / 576;
    const int ti = nt % 576;
    const int pos = ti * 16 + lm;

    floatx4 acc[3];
    #pragma unroll
    for (int j = 0; j < 3; j++)
        #pragma unroll
        for (int r = 0; r < 4; r++)
            acc[j][r] = ret_b[(wv + 4 * j) * 16 + q * 4 + r];

    const _Float16* wb = w16 + ((size_t)b * HWSZ + pos) * 320;
    for (int s = 0; s < 10; s++) {
        const int k0 = s * 32;
        const half8 bf = *(const half8*)(wb + k0 + q * 8);
        #pragma unroll
        for (int j = 0; j < 3; j++) {
            const half8 af = *(const half8*)(rw16 + (size_t)((wv + 4 * j) * 16 + lm) * 320 + k0 + q * 8);
            acc[j] = __builtin_amdgcn_mfma_f32_16x16x32_f16(af, bf, acc[j], 0, 0, 0);
        }
    }

    const _Float16* ip = i2h16 + ((size_t)b * HWSZ + pos) * 192;
    const half4 vr = *(const half4*)(ip + wv * 16 + q * 4);
    const half4 vu = *(const half4*)(ip + 64 + wv * 16 + q * 4);
    const half4 vm = *(const half4*)(ip + 128 + wv * 16 + q * 4);
    half4 pk;
    #pragma unroll
    for (int r = 0; r < 4; r++) {
        const int c = wv * 16 + q * 4 + r;
        const float gr = acc[0][r], gu = acc[1][r], gm = acc[2][r];
        const float rg = 1.0f / (1.0f + expf(-((float)vr[r] + gr)));
        const float ug = 1.0f / (1.0f + expf(-((float)vu[r] + gu)));
        const float mg = tanhf((float)vm[r] + rg * gm);
        const size_t hi = ((size_t)b * 64 + c) * HWSZ + pos;
        const float nh = ug * h[hi] + (1.0f - ug) * mg;
        h[hi] = nh;
        outs[(((size_t)b * TT + t) * 64 + c) * HWSZ + pos] = nh;
        if (t == TT - 1) last_h[hi] = nh;
        pk[r] = (_Float16)nh;
    }
    *(half4*)(h16 + ((size_t)b * HWSZ + pos) * 64 + wv * 16 + q * 4) = pk;
}

extern "C" void kernel_launch(void* const* d_in, const int* in_sizes, int n_in,
                              void* d_out, int out_size, void* d_ws, size_t ws_size,
                              hipStream_t stream) {
    const float* inputs  = (const float*)d_in[0];
    const float* i2h_w   = (const float*)d_in[1];
    const float* i2h_b   = (const float*)d_in[2];
    const float* i2f_w   = (const float*)d_in[3];
    const float* i2f_b   = (const float*)d_in[4];
    const float* h2f_w   = (const float*)d_in[5];
    const float* h2f_b   = (const float*)d_in[6];
    const float* flows_w = (const float*)d_in[7];
    const float* flows_b = (const float*)d_in[8];
    const float* ret_w   = (const float*)d_in[9];
    const float* ret_b   = (const float*)d_in[10];

    float* out = (float*)d_out;

    // workspace layout (bytes), total ~103.5 MB
    char* base = (char*)d_ws;
    float*    h        = (float*)base;      base += 9437184;    // 4*64*9216 f32
    _Float16* i2h16    = (_Float16*)base;   base += 14155776;   // 4*9216*192 f16
    float*    flowsb   = (float*)base;      base += 1474560;    // 4*10*9216 f32
    _Float16* warped16 = (_Float16*)base;   base += 23592960;   // 4*9216*320 f16
    _Float16* f116     = (_Float16*)base;   base += 2359296;    // 4*9216*32 f16
    _Float16* x16      = (_Float16*)base;   base += 47185920;   // 40*9216*64 f16
    _Float16* h16      = (_Float16*)base;   base += 4718592;    // 4*9216*64 f16
    _Float16* wi16     = (_Float16*)base;   base += 102400;     // 32*1600
    _Float16* wh16     = (_Float16*)base;   base += 102400;
    _Float16* wA16     = (_Float16*)base;   base += 221184;     // 192*576
    _Float16* rw16     = (_Float16*)base;   base += 122880;     // 192*320
    _Float16* fw16     = (_Float16*)base;   base += 25600;      // 16*800

    float* outs   = out;
    float* last_h = out + (size_t)BB * TT * 64 * HWSZ;

    hipMemsetAsync(h,   0, 9437184, stream);
    hipMemsetAsync(h16, 0, 4718592, stream);

    prep_weights<<<1122, 256, 0, stream>>>(i2f_w, h2f_w, i2h_w, ret_w, flows_w,
                                           wi16, wh16, wA16, rw16, fw16);
    prep_x16<<<1440, 256, 0, stream>>>(inputs, x16);

    for (int t = 0; t < TT; t++) {
        i2h_mfma<<<2304, 256, 0, stream>>>(x16, wA16, i2h_b, i2h16, t);
        f1_mfma<<<2304, 256, 0, stream>>>(x16, h16, wi16, wh16, i2f_b, h2f_b, f116, t);
        flows_mfma<<<2304, 256, 0, stream>>>(f116, fw16, flows_b, flowsb);
        warp_kernel<<<dim3(72, LL, BB), 256, 0, stream>>>(h16, flowsb, warped16);
        gate_mfma<<<2304, 256, 0, stream>>>(warped16, rw16, ret_b, i2h16, h, h16, outs, last_h, t);
    }
}

// Round 2
// 1543.306 us; speedup vs baseline: 1.9674x; 1.7101x over previous
//
#include <hip/hip_runtime.h>
#include <math.h>

#define BB 4
#define TT 10
#define HH 96
#define WW 96
#define HWSZ 9216
#define LL 5

typedef _Float16 half8 __attribute__((ext_vector_type(8)));
typedef _Float16 half4 __attribute__((ext_vector_type(4)));
typedef float floatx4 __attribute__((ext_vector_type(4)));

// ---------------- prep: weights -> f16, MFMA-friendly [co][k] layouts ----------------
// wi16/wh16: [co=32][k=1600], k = tap*64 + ci   (tap = ky*5+kx)
// wA16:      [co=192][k=576], k = tap*64 + ci   (tap = ky*3+kx)
// rw16:      [co=192][k=320], k = l*64 + c
// fw16:      [co=16(10 live)][k=800], k = tap*32 + ci
__global__ __launch_bounds__(256) void prep_weights(const float* __restrict__ i2f_w,
                                                    const float* __restrict__ h2f_w,
                                                    const float* __restrict__ i2h_w,
                                                    const float* __restrict__ ret_w,
                                                    const float* __restrict__ flows_w,
                                                    _Float16* __restrict__ wi16,
                                                    _Float16* __restrict__ wh16,
                                                    _Float16* __restrict__ wA16,
                                                    _Float16* __restrict__ rw16,
                                                    _Float16* __restrict__ fw16) {
    const int id = blockIdx.x * 256 + threadIdx.x;   // 0..287231
    if (id < 51200) {
        const int co = id / 1600, k = id % 1600, tap = k >> 6, ci = k & 63;
        wi16[id] = (_Float16)i2f_w[(co * 64 + ci) * 25 + tap];
    } else if (id < 102400) {
        const int r = id - 51200;
        const int co = r / 1600, k = r % 1600, tap = k >> 6, ci = k & 63;
        wh16[r] = (_Float16)h2f_w[(co * 64 + ci) * 25 + tap];
    } else if (id < 212992) {
        const int r = id - 102400;
        const int co = r / 576, k = r % 576, tap = k >> 6, ci = k & 63;
        wA16[r] = (_Float16)i2h_w[(co * 64 + ci) * 9 + tap];
    } else if (id < 274432) {
        const int r = id - 212992;
        rw16[r] = (_Float16)ret_w[r];   // already [co][320] with k = l*64+c
    } else {
        const int r = id - 274432;      // 0..12799
        const int co = r / 800, k = r % 800, tap = k >> 5, ci = k & 31;
        fw16[r] = (co < 10) ? (_Float16)flows_w[(co * 32 + ci) * 25 + tap] : (_Float16)0.0f;
    }
}

// ---------------- prep: x -> f16 channel-last x16[img][pos][ci], img flat ----
__global__ __launch_bounds__(256) void prep_x16(const float* __restrict__ x,
                                                _Float16* __restrict__ x16) {
    const int id = blockIdx.x * 256 + threadIdx.x;   // 0..368639
    const int img = id / HWSZ, pos = id % HWSZ;
    const float* src = x + (size_t)img * 64 * HWSZ + pos;
    _Float16* dst = x16 + ((size_t)img * HWSZ + pos) * 64;
    #pragma unroll
    for (int i = 0; i < 8; i++) {
        half8 v;
        #pragma unroll
        for (int j = 0; j < 8; j++)
            v[j] = (_Float16)src[(size_t)(i * 8 + j) * HWSZ];
        *(half8*)(dst + i * 8) = v;
    }
}

// ---------------- i2h: 3x3 conv, LDS-staged implicit GEMM ---------------------------
// Block = 16x4 pixel out-tile (grid 4b x 144 tiles = 576). Patch 6x18x64ch in LDS,
// XOR-swizzled. Wave wv owns m-tiles m0..m0+2 x all 4 n-rows (216 MFMA/wave).
// image remap preserved: step t, batch b reads flat image q = t*4 + b
__global__ __launch_bounds__(256) void i2h_mfma(const _Float16* __restrict__ x16,
                                                const _Float16* __restrict__ wA16,
                                                const float* __restrict__ bias,
                                                _Float16* __restrict__ i2h16, int t) {
    __shared__ _Float16 patch[108 * 64];            // 6*18 pixels * 64ch, 13824 B
    const int tid = threadIdx.x;
    const int wv = tid >> 6, ln = tid & 63;
    const int lm = ln & 15, q = ln >> 4;
    const int b  = blockIdx.x / 144;
    const int ti = blockIdx.x % 144;
    const int y0 = (ti / 6) * 4, x0 = (ti % 6) * 16;
    const _Float16* xb = x16 + (size_t)(t * BB + b) * HWSZ * 64;

    // stage: rows y0-1..y0+4, cols x0-1..x0+16, zero-filled OOB, swizzled chunks
    for (int m = tid; m < 864; m += 256) {
        const int p = m >> 3, c = m & 7;            // pixel, 16B chunk
        const int pr = p / 18, pc = p % 18;
        const int gy = y0 - 1 + pr, gx = x0 - 1 + pc;
        half8 v = {};
        if (gy >= 0 && gy < HH && gx >= 0 && gx < WW)
            v = *(const half8*)(xb + (size_t)(gy * WW + gx) * 64 + c * 8);
        *(half8*)(&patch[p * 64 + ((c * 8) ^ ((p & 7) << 3))]) = v;
    }
    __syncthreads();

    const int m0 = wv * 3;
    floatx4 acc[4][3];
    #pragma unroll
    for (int n = 0; n < 4; n++)
        #pragma unroll
        for (int j = 0; j < 3; j++)
            #pragma unroll
            for (int r = 0; r < 4; r++)
                acc[n][j][r] = bias[(m0 + j) * 16 + q * 4 + r];

    for (int tap = 0; tap < 9; tap++) {
        const int ky = tap / 3, kx = tap % 3;       // patch-space offsets
        half8 a[3][2];
        #pragma unroll
        for (int j = 0; j < 3; j++)
            #pragma unroll
            for (int h = 0; h < 2; h++)
                a[j][h] = *(const half8*)(wA16 + (size_t)((m0 + j) * 16 + lm) * 576
                                          + tap * 64 + h * 32 + q * 8);
        #pragma unroll
        for (int n = 0; n < 4; n++) {
            const int p = (n + ky) * 18 + lm + kx;
            const int sw = (p & 7) << 3;
            const half8 bf0 = *(const half8*)(&patch[p * 64 + ((q * 8) ^ sw)]);
            const half8 bf1 = *(const half8*)(&patch[p * 64 + ((32 + q * 8) ^ sw)]);
            #pragma unroll
            for (int j = 0; j < 3; j++) {
                acc[n][j] = __builtin_amdgcn_mfma_f32_16x16x32_f16(a[j][0], bf0, acc[n][j], 0, 0, 0);
                acc[n][j] = __builtin_amdgcn_mfma_f32_16x16x32_f16(a[j][1], bf1, acc[n][j], 0, 0, 0);
            }
        }
    }
    #pragma unroll
    for (int n = 0; n < 4; n++) {
        const int pos = (y0 + n) * WW + x0 + lm;
        _Float16* op = i2h16 + ((size_t)b * HWSZ + pos) * 192;
        #pragma unroll
        for (int j = 0; j < 3; j++) {
            half4 pk;
            #pragma unroll
            for (int r = 0; r < 4; r++) pk[r] = (_Float16)acc[n][j][r];
            *(half4*)(op + (m0 + j) * 16 + q * 4) = pk;
        }
    }
}

// ---------------- f1: tanh(conv5x5(x_t)+conv5x5(h)), LDS-staged --------------------
// Block = 16x4 out-tile (grid 576). Two patches 8x20x64ch (x_t, h) in LDS.
// Wave = (source, ci-half): 25 taps x 2m x 4n = 200 MFMA/wave; padded LDS reduce.
__global__ __launch_bounds__(256) void f1_mfma(const _Float16* __restrict__ x16,
                                               const _Float16* __restrict__ h16,
                                               const _Float16* __restrict__ wi16,
                                               const _Float16* __restrict__ wh16,
                                               const float* __restrict__ bi,
                                               const float* __restrict__ bh,
                                               _Float16* __restrict__ f116, int t) {
    __shared__ _Float16 sm[20480];                  // 2 x (160 pixels x 64ch) = 40960 B
    const int tid = threadIdx.x;
    const int wv = tid >> 6, ln = tid & 63;
    const int lm = ln & 15, q = ln >> 4;
    const int b  = blockIdx.x / 144;
    const int ti = blockIdx.x % 144;
    const int y0 = (ti / 6) * 4, x0 = (ti % 6) * 16;

    const _Float16* src0 = x16 + (size_t)(b * TT + t) * HWSZ * 64;  // x_t (natural order)
    const _Float16* src1 = h16 + (size_t)b * HWSZ * 64;

    // stage both patches: rows y0-2..y0+5, cols x0-2..x0+17
    for (int m = tid; m < 2560; m += 256) {
        const int sid = m / 1280, mm = m % 1280;
        const int p = mm >> 3, c = mm & 7;
        const int pr = p / 20, pc = p % 20;
        const int gy = y0 - 2 + pr, gx = x0 - 2 + pc;
        const _Float16* src = sid ? src1 : src0;
        half8 v = {};
        if (gy >= 0 && gy < HH && gx >= 0 && gx < WW)
            v = *(const half8*)(src + (size_t)(gy * WW + gx) * 64 + c * 8);
        *(half8*)(&sm[sid * 10240 + p * 64 + ((c * 8) ^ ((p & 7) << 3))]) = v;
    }
    __syncthreads();

    const int sid = wv >> 1;                        // 0: x-conv, 1: h-conv
    const int ci0 = (wv & 1) * 32;                  // ci-half (in halves)
    const _Float16* wt = sid ? wh16 : wi16;
    const _Float16* pb = &sm[sid * 10240];

    floatx4 acc[4][2] = {};
    for (int tap = 0; tap < 25; tap++) {
        const int ky = tap / 5, kx = tap % 5;       // patch-space offsets
        const half8 a0 = *(const half8*)(wt + (size_t)(0 * 16 + lm) * 1600 + tap * 64 + ci0 + q * 8);
        const half8 a1 = *(const half8*)(wt + (size_t)(1 * 16 + lm) * 1600 + tap * 64 + ci0 + q * 8);
        #pragma unroll
        for (int n = 0; n < 4; n++) {
            const int p = (n + ky) * 20 + lm + kx;
            const half8 bf = *(const half8*)(&pb[p * 64 + ((ci0 + q * 8) ^ ((p & 7) << 3))]);
            acc[n][0] = __builtin_amdgcn_mfma_f32_16x16x32_f16(a0, bf, acc[n][0], 0, 0, 0);
            acc[n][1] = __builtin_amdgcn_mfma_f32_16x16x32_f16(a1, bf, acc[n][1], 0, 0, 0);
        }
    }
    __syncthreads();                                // all patch reads done; sm reusable
    float* redf = (float*)sm;                       // [3 waves][64 lanes][stride 33]
    if (wv) {
        #pragma unroll
        for (int n = 0; n < 4; n++)
            #pragma unroll
            for (int mt = 0; mt < 2; mt++)
                #pragma unroll
                for (int r = 0; r < 4; r++)
                    redf[((wv - 1) * 64 + ln) * 33 + n * 8 + mt * 4 + r] = acc[n][mt][r];
    }
    __syncthreads();
    if (wv == 0) {
        #pragma unroll
        for (int w = 0; w < 3; w++)
            #pragma unroll
            for (int n = 0; n < 4; n++)
                #pragma unroll
                for (int mt = 0; mt < 2; mt++)
                    #pragma unroll
                    for (int r = 0; r < 4; r++)
                        acc[n][mt][r] += redf[(w * 64 + ln) * 33 + n * 8 + mt * 4 + r];
        #pragma unroll
        for (int n = 0; n < 4; n++) {
            const int pos = (y0 + n) * WW + x0 + lm;
            _Float16* op = f116 + ((size_t)b * HWSZ + pos) * 32;
            #pragma unroll
            for (int mt = 0; mt < 2; mt++) {
                half4 pk;
                #pragma unroll
                for (int r = 0; r < 4; r++)
                    pk[r] = (_Float16)tanhf(acc[n][mt][r] + bi[mt * 16 + q * 4 + r]
                                                          + bh[mt * 16 + q * 4 + r]);
                *(half4*)(op + mt * 16 + q * 4) = pk;
            }
        }
    }
}

// ---------------- flows: conv5x5(f1,32->10), one BLOCK per n-tile, 4-way tap-split ----
__global__ __launch_bounds__(256) void flows_mfma(const _Float16* __restrict__ f116,
                                                  const _Float16* __restrict__ fw16,
                                                  const float* __restrict__ bias,
                                                  float* __restrict__ out) {
    __shared__ float red[3][64][4];
    const int wv = threadIdx.x >> 6;
    const int ln = threadIdx.x & 63;
    const int lm = ln & 15, q = ln >> 4;
    const int nt = blockIdx.x;                   // 0..2303
    const int b  = nt / 576;
    const int ti = nt % 576;
    const int y  = ti / 6, xx = (ti % 6) * 16;

    floatx4 acc = {};
    const _Float16* fb = f116 + (size_t)b * HWSZ * 32;
    const int t0 = (25 * wv) / 4, t1 = (25 * (wv + 1)) / 4;   // 6/6/6/7 taps
    for (int tap = t0; tap < t1; tap++) {
        const int ky = tap / 5 - 2, kx = tap % 5 - 2;
        const int gy = y + ky, gx = xx + lm + kx;
        half8 bf = {};
        if (gy >= 0 && gy < HH && gx >= 0 && gx < WW)
            bf = *(const half8*)(fb + (size_t)(gy * WW + gx) * 32 + q * 8);
        const half8 af = *(const half8*)(fw16 + (size_t)lm * 800 + tap * 32 + q * 8);
        acc = __builtin_amdgcn_mfma_f32_16x16x32_f16(af, bf, acc, 0, 0, 0);
    }
    if (wv) {
        #pragma unroll
        for (int r = 0; r < 4; r++) red[wv - 1][ln][r] = acc[r];
    }
    __syncthreads();
    if (wv == 0) {
        #pragma unroll
        for (int w = 0; w < 3; w++)
            #pragma unroll
            for (int r = 0; r < 4; r++) acc[r] += red[w][ln][r];
        const int pos = y * WW + xx + lm;
        #pragma unroll
        for (int r = 0; r < 4; r++) {
            const int c = q * 4 + r;
            if (c < 10)
                out[((size_t)b * 10 + c) * HWSZ + pos] = acc[r] + bias[c];
        }
    }
}

// ---------------- warp: bilinear warp of h16 by -flow, 2 threads per (b,l,pos) --------
__global__ __launch_bounds__(256) void warp_kernel(const _Float16* __restrict__ h16,
                                                   const float* __restrict__ flows,
                                                   _Float16* __restrict__ w16) {
    const int id = blockIdx.x * 256 + threadIdx.x;   // 0..18431
    const int p  = id >> 1;
    const int hf = (id & 1) * 32;                    // channel half: 0 or 32
    const int l = blockIdx.y;
    const int b = blockIdx.z;
    const int y = p / WW, xx = p % WW;
    const float f0  = -flows[((size_t)b * 10 + l * 2 + 0) * HWSZ + p];
    const float f1v = -flows[((size_t)b * 10 + l * 2 + 1) * HWSZ + p];
    const float nx = 2.0f * ((float)xx + f0)  / (float)(WW - 1) - 1.0f;
    const float ny = 2.0f * ((float)y  + f1v) / (float)(HH - 1) - 1.0f;
    const float fx = (nx + 1.0f) * (WW * 0.5f) - 0.5f;
    const float fy = (ny + 1.0f) * (HH * 0.5f) - 0.5f;
    const float x0f = floorf(fx), y0f = floorf(fy);
    const float wx = fx - x0f, wy = fy - y0f;
    const int x0 = (int)x0f, y0 = (int)y0f;

    int   off[4];
    float wgt[4];
    #pragma unroll
    for (int k = 0; k < 4; k++) {
        const int yi = y0 + (k >> 1);
        const int xi = x0 + (k & 1);
        const bool ok = (xi >= 0 && xi < WW && yi >= 0 && yi < HH);
        const int yc = min(max(yi, 0), HH - 1);
        const int xc = min(max(xi, 0), WW - 1);
        off[k] = yc * WW + xc;
        const float wk = ((k & 1) ? wx : 1.0f - wx) * ((k >> 1) ? wy : 1.0f - wy);
        wgt[k] = ok ? wk : 0.0f;
    }
    const _Float16* hb = h16 + (size_t)b * HWSZ * 64 + hf;
    _Float16* dst = w16 + ((size_t)b * HWSZ + p) * 320 + l * 64 + hf;
    #pragma unroll
    for (int i = 0; i < 4; i++) {
        const half8 v0 = *(const half8*)(hb + (size_t)off[0] * 64 + i * 8);
        const half8 v1 = *(const half8*)(hb + (size_t)off[1] * 64 + i * 8);
        const half8 v2 = *(const half8*)(hb + (size_t)off[2] * 64 + i * 8);
        const half8 v3 = *(const half8*)(hb + (size_t)off[3] * 64 + i * 8);
        half8 o;
        #pragma unroll
        for (int j = 0; j < 8; j++)
            o[j] = (_Float16)((float)v0[j] * wgt[0] + (float)v1[j] * wgt[1]
                            + (float)v2[j] * wgt[2] + (float)v3[j] * wgt[3]);
        *(half8*)(dst + i * 8) = o;
    }
}

// ---------------- h2h (1x1, 320->192) as MFMA + fused GRU gates -----------------------
// One BLOCK per n-tile; wave w owns m-tiles {w, w+4, w+8} = (r,u,m) for channels 16w..
__global__ __launch_bounds__(256) void gate_mfma(const _Float16* __restrict__ w16,
                                                 const _Float16* __restrict__ rw16,
                                                 const float* __restrict__ ret_b,
                                                 const _Float16* __restrict__ i2h16,
                                                 float* __restrict__ h,
                                                 _Float16* __restrict__ h16,
                                                 float* __restrict__ outs,
                                                 float* __restrict__ last_h, int t) {
    const int wv = threadIdx.x >> 6;
    const int ln = threadIdx.x & 63;
    const int lm = ln & 15, q = ln >> 4;
    const int nt = blockIdx.x;                   // 0..2303
    const int b  = nt / 576;
    const int ti = nt % 576;
    const int pos = ti * 16 + lm;

    floatx4 acc[3];
    #pragma unroll
    for (int j = 0; j < 3; j++)
        #pragma unroll
        for (int r = 0; r < 4; r++)
            acc[j][r] = ret_b[(wv + 4 * j) * 16 + q * 4 + r];

    const _Float16* wb = w16 + ((size_t)b * HWSZ + pos) * 320;
    for (int s = 0; s < 10; s++) {
        const int k0 = s * 32;
        const half8 bf = *(const half8*)(wb + k0 + q * 8);
        #pragma unroll
        for (int j = 0; j < 3; j++) {
            const half8 af = *(const half8*)(rw16 + (size_t)((wv + 4 * j) * 16 + lm) * 320 + k0 + q * 8);
            acc[j] = __builtin_amdgcn_mfma_f32_16x16x32_f16(af, bf, acc[j], 0, 0, 0);
        }
    }

    const _Float16* ip = i2h16 + ((size_t)b * HWSZ + pos) * 192;
    const half4 vr = *(const half4*)(ip + wv * 16 + q * 4);
    const half4 vu = *(const half4*)(ip + 64 + wv * 16 + q * 4);
    const half4 vm = *(const half4*)(ip + 128 + wv * 16 + q * 4);
    half4 pk;
    #pragma unroll
    for (int r = 0; r < 4; r++) {
        const int c = wv * 16 + q * 4 + r;
        const float gr = acc[0][r], gu = acc[1][r], gm = acc[2][r];
        const float rg = 1.0f / (1.0f + expf(-((float)vr[r] + gr)));
        const float ug = 1.0f / (1.0f + expf(-((float)vu[r] + gu)));
        const float mg = tanhf((float)vm[r] + rg * gm);
        const size_t hi = ((size_t)b * 64 + c) * HWSZ + pos;
        const float nh = ug * h[hi] + (1.0f - ug) * mg;
        h[hi] = nh;
        outs[(((size_t)b * TT + t) * 64 + c) * HWSZ + pos] = nh;
        if (t == TT - 1) last_h[hi] = nh;
        pk[r] = (_Float16)nh;
    }
    *(half4*)(h16 + ((size_t)b * HWSZ + pos) * 64 + wv * 16 + q * 4) = pk;
}

extern "C" void kernel_launch(void* const* d_in, const int* in_sizes, int n_in,
                              void* d_out, int out_size, void* d_ws, size_t ws_size,
                              hipStream_t stream) {
    const float* inputs  = (const float*)d_in[0];
    const float* i2h_w   = (const float*)d_in[1];
    const float* i2h_b   = (const float*)d_in[2];
    const float* i2f_w   = (const float*)d_in[3];
    const float* i2f_b   = (const float*)d_in[4];
    const float* h2f_w   = (const float*)d_in[5];
    const float* h2f_b   = (const float*)d_in[6];
    const float* flows_w = (const float*)d_in[7];
    const float* flows_b = (const float*)d_in[8];
    const float* ret_w   = (const float*)d_in[9];
    const float* ret_b   = (const float*)d_in[10];

    float* out = (float*)d_out;

    // workspace layout (bytes), total ~103.5 MB
    char* base = (char*)d_ws;
    float*    h        = (float*)base;      base += 9437184;    // 4*64*9216 f32
    _Float16* i2h16    = (_Float16*)base;   base += 14155776;   // 4*9216*192 f16
    float*    flowsb   = (float*)base;      base += 1474560;    // 4*10*9216 f32
    _Float16* warped16 = (_Float16*)base;   base += 23592960;   // 4*9216*320 f16
    _Float16* f116     = (_Float16*)base;   base += 2359296;    // 4*9216*32 f16
    _Float16* x16      = (_Float16*)base;   base += 47185920;   // 40*9216*64 f16
    _Float16* h16      = (_Float16*)base;   base += 4718592;    // 4*9216*64 f16
    _Float16* wi16     = (_Float16*)base;   base += 102400;     // 32*1600
    _Float16* wh16     = (_Float16*)base;   base += 102400;
    _Float16* wA16     = (_Float16*)base;   base += 221184;     // 192*576
    _Float16* rw16     = (_Float16*)base;   base += 122880;     // 192*320
    _Float16* fw16     = (_Float16*)base;   base += 25600;      // 16*800

    float* outs   = out;
    float* last_h = out + (size_t)BB * TT * 64 * HWSZ;

    hipMemsetAsync(h,   0, 9437184, stream);
    hipMemsetAsync(h16, 0, 4718592, stream);

    prep_weights<<<1122, 256, 0, stream>>>(i2f_w, h2f_w, i2h_w, ret_w, flows_w,
                                           wi16, wh16, wA16, rw16, fw16);
    prep_x16<<<1440, 256, 0, stream>>>(inputs, x16);

    for (int t = 0; t < TT; t++) {
        i2h_mfma<<<576, 256, 0, stream>>>(x16, wA16, i2h_b, i2h16, t);
        f1_mfma<<<576, 256, 0, stream>>>(x16, h16, wi16, wh16, i2f_b, h2f_b, f116, t);
        flows_mfma<<<2304, 256, 0, stream>>>(f116, fw16, flows_b, flowsb);
        warp_kernel<<<dim3(72, LL, BB), 256, 0, stream>>>(h16, flowsb, warped16);
        gate_mfma<<<2304, 256, 0, stream>>>(warped16, rw16, ret_b, i2h16, h, h16, outs, last_h, t);
    }
}